// Round 4
// baseline (1752.174 us; speedup 1.0000x reference)
//
#include <hip/hip_runtime.h>

#define PRE   2048
#define POST  2048
#define BATCH 64
#define HIST  50

// output layout (floats), in reference return order
#define OFF_SYN      0           // [64][2048]
#define OFF_PRE_ACT  131072      // [2048]
#define OFF_POST_ACT 133120      // [2048]
#define OFF_HIST     135168      // [2048][2048][50]
#define OFF_LIFE     209850368   // [2048][2048]
#define OFF_AVG      214044672   // [2048][2048]

// native clang vector type: valid for __builtin_nontemporal_load/store
typedef float f32x4 __attribute__((ext_vector_type(4)));

// ---------------------------------------------------------------------------
// Kernel 1: batch means + EMA activity traces; also zero the synaptic_current
// region (d_out poisoned 0xAA each call; k_matmul accumulates atomically).
// grid 16 x 256
// ---------------------------------------------------------------------------
__global__ __launch_bounds__(256) void k_means(
    const float* __restrict__ pre, const float* __restrict__ post,
    const float* __restrict__ pre_act, const float* __restrict__ post_act,
    float* __restrict__ out, float* __restrict__ ws_means) {
  const int t = blockIdx.x * 256 + threadIdx.x;  // 0..4095

  f32x4* outz = reinterpret_cast<f32x4*>(out + OFF_SYN);
  const f32x4 z = {0.f, 0.f, 0.f, 0.f};
#pragma unroll
  for (int i = 0; i < 8; ++i) outz[t + i * 4096] = z;

  if (t < PRE) {
    float s = 0.f;
#pragma unroll 16
    for (int b = 0; b < BATCH; ++b) s += pre[b * PRE + t];
    const float m = s * (1.0f / BATCH);
    ws_means[t] = m;
    out[OFF_PRE_ACT + t] = 0.99f * pre_act[t] + 0.01f * m;
  } else {
    const int c = t - PRE;
    float s = 0.f;
#pragma unroll 16
    for (int b = 0; b < BATCH; ++b) s += post[b * POST + c];
    const float m = s * (1.0f / BATCH);
    ws_means[PRE + c] = m;
    out[OFF_POST_ACT + c] = 0.99f * post_act[c] + 0.01f * m;
  }
}

// ---------------------------------------------------------------------------
// Kernel 2: synaptic_current = pre_spikes @ (W*M). fp32 vector FMA (no fp32
// MFMA on CDNA4). Grid 512 = 16 j-tiles(128) x 32 k-splits(64) -> 2 blocks/CU
// (32 KB LDS), 8 waves/CU for latency hiding. acc[4][8] register tile.
// ---------------------------------------------------------------------------
__global__ __launch_bounds__(256) void k_matmul(
    const float* __restrict__ pre, const float* __restrict__ W,
    const float* __restrict__ M, float* __restrict__ out) {
  __shared__ float ew[64 * 128];  // 32 KB

  const int jt = blockIdx.x & 15;  // 16 j-tiles of 128
  const int ks = blockIdx.x >> 4;  // 32 k-splits of 64
  const int j0 = jt * 128;
  const int k0 = ks * 64;
  const int t = threadIdx.x;

  // stage ew = W*M for [k0:k0+64][j0:j0+128]: 8192 floats = 2048 float4
#pragma unroll
  for (int it = 0; it < 8; ++it) {
    const int lin = (t + it * 256) * 4;  // 0..8188
    const int kk = lin >> 7;
    const int jj = lin & 127;
    const float4 w4 = *reinterpret_cast<const float4*>(&W[(k0 + kk) * POST + j0 + jj]);
    const float4 m4 = *reinterpret_cast<const float4*>(&M[(k0 + kk) * POST + j0 + jj]);
    float4 e;
    e.x = w4.x * m4.x; e.y = w4.y * m4.y; e.z = w4.z * m4.z; e.w = w4.w * m4.w;
    *reinterpret_cast<float4*>(&ew[kk * 128 + jj]) = e;
  }
  __syncthreads();

  const int tj = t & 15;   // 16 j-threads * 8 cols = 128
  const int tb = t >> 4;   // 16 b-groups * 4 rows = 64
  const int jb = tj * 8;
  const int bb0 = tb * 4;

  float acc[4][8];
#pragma unroll
  for (int r = 0; r < 4; ++r)
#pragma unroll
    for (int c = 0; c < 8; ++c) acc[r][c] = 0.f;

  const float4* ew4 = reinterpret_cast<const float4*>(ew);

#pragma unroll
  for (int kk4 = 0; kk4 < 16; ++kk4) {
    float4 pr[4];
#pragma unroll
    for (int r = 0; r < 4; ++r)
      pr[r] = *reinterpret_cast<const float4*>(&pre[(bb0 + r) * PRE + k0 + kk4 * 4]);
#pragma unroll
    for (int e = 0; e < 4; ++e) {
      const int kk = kk4 * 4 + e;
      const float4 e0 = ew4[kk * 32 + tj * 2];
      const float4 e1 = ew4[kk * 32 + tj * 2 + 1];
#pragma unroll
      for (int r = 0; r < 4; ++r) {
        const float pv = (e == 0) ? pr[r].x : (e == 1) ? pr[r].y : (e == 2) ? pr[r].z : pr[r].w;
        acc[r][0] += pv * e0.x; acc[r][1] += pv * e0.y;
        acc[r][2] += pv * e0.z; acc[r][3] += pv * e0.w;
        acc[r][4] += pv * e1.x; acc[r][5] += pv * e1.y;
        acc[r][6] += pv * e1.z; acc[r][7] += pv * e1.w;
      }
    }
  }

#pragma unroll
  for (int r = 0; r < 4; ++r)
#pragma unroll
    for (int c = 0; c < 8; ++c)
      unsafeAtomicAdd(&out[OFF_SYN + (bb0 + r) * POST + j0 + jb + c], acc[r][c]);
}

// ---------------------------------------------------------------------------
// Kernel 3 (dominant): history copy + idx-slice replace + fused avg + life.
// 320 threads/block, 256 pairs/block = 12800 floats = 3200 float4 = exactly
// 10 float4/thread (uniform, fully unrolled -> 10 nt-loads in flight).
// One magic-div per float4. Flat LDS mirror (float4 writes, conflict-free);
// phase-B float2 reads at dword-stride 50 (gcd(50,32)=2 -> 2-way, free).
// ---------------------------------------------------------------------------
__global__ __launch_bounds__(320) void k_history(
    const float* __restrict__ hist_in, const float* __restrict__ mask,
    const float* __restrict__ life_in, const float* __restrict__ ws_means,
    const int* __restrict__ corr_idx, float* __restrict__ out) {
  __shared__ float lds[256 * HIST];  // 51200 B -> 3 blocks/CU

  const int t = threadIdx.x;
  const int pair0 = blockIdx.x * 256;
  const int i_row = pair0 >> 11;     // 256 | 2048 -> constant per block
  const int jbase = pair0 & 2047;

  int idx = corr_idx[0] % HIST;
  if (idx < 0) idx += HIST;

  const float mp_i = ws_means[i_row];
  const float* __restrict__ hsrc = hist_in + (size_t)pair0 * HIST;
  float* __restrict__ hdst = out + OFF_HIST + (size_t)pair0 * HIST;
  const float* __restrict__ mpost = ws_means + PRE + jbase;

  const f32x4* __restrict__ hsrc4 = reinterpret_cast<const f32x4*>(hsrc);
  f32x4* __restrict__ hdst4 = reinterpret_cast<f32x4*>(hdst);
  f32x4* __restrict__ lds4 = reinterpret_cast<f32x4*>(lds);

  // Phase A: 3200 float4, 10 per thread, fully unrolled
#pragma unroll
  for (int it = 0; it < 10; ++it) {
    const int v = t + it * 320;       // 0..3199
    const int f = v * 4;              // flat float index
    f32x4 x = __builtin_nontemporal_load(&hsrc4[v]);
    const int p0 = f / 50;            // one magic-div per float4
    const int h0 = f - p0 * 50;       // 0..49
#pragma unroll
    for (int e = 0; e < 4; ++e) {
      int h = h0 + e;
      int p = p0;
      if (h >= 50) { h -= 50; ++p; }
      if (h == idx) x[e] = mp_i * mpost[p];
    }
    lds4[v] = x;
    __builtin_nontemporal_store(x, &hdst4[v]);
  }
  __syncthreads();

  // Phase B: per-pair mean + lifetimes (threads 0..255)
  if (t < 256) {
    const float2* __restrict__ l2 = reinterpret_cast<const float2*>(lds);
    float s = 0.f;
#pragma unroll
    for (int u = 0; u < 25; ++u) {
      const float2 y = l2[t * 25 + u];
      s += y.x + y.y;
    }
    const size_t pg = (size_t)pair0 + t;
    out[OFF_AVG + pg] = s * (1.0f / HIST);
    out[OFF_LIFE + pg] = life_in[pg] + mask[pg];
  }
}

// ---------------------------------------------------------------------------
extern "C" void kernel_launch(void* const* d_in, const int* in_sizes, int n_in,
                              void* d_out, int out_size, void* d_ws, size_t ws_size,
                              hipStream_t stream) {
  const float* pre   = (const float*)d_in[0];
  const float* post  = (const float*)d_in[1];
  // d_in[2] = current_time (unused: plasticity branch statically skipped)
  const float* W     = (const float*)d_in[3];
  const float* Mask  = (const float*)d_in[4];
  const float* preA  = (const float*)d_in[5];
  const float* postA = (const float*)d_in[6];
  const float* hist  = (const float*)d_in[7];
  const float* life  = (const float*)d_in[8];
  const int*   cidx  = (const int*)d_in[9];
  float* out = (float*)d_out;
  float* means = (float*)d_ws;  // 4096 floats scratch

  k_means<<<16, 256, 0, stream>>>(pre, post, preA, postA, out, means);
  k_matmul<<<512, 256, 0, stream>>>(pre, W, Mask, out);
  k_history<<<16384, 320, 0, stream>>>(hist, Mask, life, means, cidx, out);
}

// Round 5
// 1598.186 us; speedup vs baseline: 1.0964x; 1.0964x over previous
//
#include <hip/hip_runtime.h>

#define PRE   2048
#define POST  2048
#define BATCH 64
#define HIST  50

// output layout (floats), in reference return order
#define OFF_SYN      0           // [64][2048]
#define OFF_PRE_ACT  131072      // [2048]
#define OFF_POST_ACT 133120      // [2048]
#define OFF_HIST     135168      // [2048][2048][50]
#define OFF_LIFE     209850368   // [2048][2048]
#define OFF_AVG      214044672   // [2048][2048]

// native clang vector type (works with nontemporal builtins if needed)
typedef float f32x4 __attribute__((ext_vector_type(4)));

// ---------------------------------------------------------------------------
// Kernel 1: batch means + EMA activity traces; also zero the synaptic_current
// region (d_out poisoned 0xAA each call; k_matmul accumulates atomically).
// grid 16 x 256
// ---------------------------------------------------------------------------
__global__ __launch_bounds__(256) void k_means(
    const float* __restrict__ pre, const float* __restrict__ post,
    const float* __restrict__ pre_act, const float* __restrict__ post_act,
    float* __restrict__ out, float* __restrict__ ws_means) {
  const int t = blockIdx.x * 256 + threadIdx.x;  // 0..4095

  f32x4* outz = reinterpret_cast<f32x4*>(out + OFF_SYN);
  const f32x4 z = {0.f, 0.f, 0.f, 0.f};
#pragma unroll
  for (int i = 0; i < 8; ++i) outz[t + i * 4096] = z;

  if (t < PRE) {
    float s = 0.f;
#pragma unroll 16
    for (int b = 0; b < BATCH; ++b) s += pre[b * PRE + t];
    const float m = s * (1.0f / BATCH);
    ws_means[t] = m;
    out[OFF_PRE_ACT + t] = 0.99f * pre_act[t] + 0.01f * m;
  } else {
    const int c = t - PRE;
    float s = 0.f;
#pragma unroll 16
    for (int b = 0; b < BATCH; ++b) s += post[b * POST + c];
    const float m = s * (1.0f / BATCH);
    ws_means[PRE + c] = m;
    out[OFF_POST_ACT + c] = 0.99f * post_act[c] + 0.01f * m;
  }
}

// ---------------------------------------------------------------------------
// Kernel 2: synaptic_current = pre_spikes @ (W*M). fp32 vector FMA (no fp32
// MFMA on CDNA4). Grid 512 = 16 j-tiles(128) x 32 k-splits(64) -> 2 blocks/CU
// (32 KB LDS), 8 waves/CU for latency hiding. acc[4][8] register tile.
// ---------------------------------------------------------------------------
__global__ __launch_bounds__(256) void k_matmul(
    const float* __restrict__ pre, const float* __restrict__ W,
    const float* __restrict__ M, float* __restrict__ out) {
  __shared__ float ew[64 * 128];  // 32 KB

  const int jt = blockIdx.x & 15;  // 16 j-tiles of 128
  const int ks = blockIdx.x >> 4;  // 32 k-splits of 64
  const int j0 = jt * 128;
  const int k0 = ks * 64;
  const int t = threadIdx.x;

  // stage ew = W*M for [k0:k0+64][j0:j0+128]: 8192 floats = 2048 float4
#pragma unroll
  for (int it = 0; it < 8; ++it) {
    const int lin = (t + it * 256) * 4;  // 0..8188
    const int kk = lin >> 7;
    const int jj = lin & 127;
    const float4 w4 = *reinterpret_cast<const float4*>(&W[(k0 + kk) * POST + j0 + jj]);
    const float4 m4 = *reinterpret_cast<const float4*>(&M[(k0 + kk) * POST + j0 + jj]);
    float4 e;
    e.x = w4.x * m4.x; e.y = w4.y * m4.y; e.z = w4.z * m4.z; e.w = w4.w * m4.w;
    *reinterpret_cast<float4*>(&ew[kk * 128 + jj]) = e;
  }
  __syncthreads();

  const int tj = t & 15;   // 16 j-threads * 8 cols = 128
  const int tb = t >> 4;   // 16 b-groups * 4 rows = 64
  const int jb = tj * 8;
  const int bb0 = tb * 4;

  float acc[4][8];
#pragma unroll
  for (int r = 0; r < 4; ++r)
#pragma unroll
    for (int c = 0; c < 8; ++c) acc[r][c] = 0.f;

  const float4* ew4 = reinterpret_cast<const float4*>(ew);

#pragma unroll
  for (int kk4 = 0; kk4 < 16; ++kk4) {
    float4 pr[4];
#pragma unroll
    for (int r = 0; r < 4; ++r)
      pr[r] = *reinterpret_cast<const float4*>(&pre[(bb0 + r) * PRE + k0 + kk4 * 4]);
#pragma unroll
    for (int e = 0; e < 4; ++e) {
      const int kk = kk4 * 4 + e;
      const float4 e0 = ew4[kk * 32 + tj * 2];
      const float4 e1 = ew4[kk * 32 + tj * 2 + 1];
#pragma unroll
      for (int r = 0; r < 4; ++r) {
        const float pv = (e == 0) ? pr[r].x : (e == 1) ? pr[r].y : (e == 2) ? pr[r].z : pr[r].w;
        acc[r][0] += pv * e0.x; acc[r][1] += pv * e0.y;
        acc[r][2] += pv * e0.z; acc[r][3] += pv * e0.w;
        acc[r][4] += pv * e1.x; acc[r][5] += pv * e1.y;
        acc[r][6] += pv * e1.z; acc[r][7] += pv * e1.w;
      }
    }
  }

#pragma unroll
  for (int r = 0; r < 4; ++r)
#pragma unroll
    for (int c = 0; c < 8; ++c)
      unsafeAtomicAdd(&out[OFF_SYN + (bb0 + r) * POST + j0 + jb + c], acc[r][c]);
}

// ---------------------------------------------------------------------------
// Kernel 3 (dominant): history copy + idx-slice replace + fused avg + life.
// NO full LDS mirror: per-pair sums accumulate via ds_add_f32 atomics into a
// 1 KB sums[256] array (each f4 spans <=2 pairs). LDS 51.2 KB -> 1 KB, so
// occupancy is thread-limited (~6 blocks/CU, 30 waves) instead of 3 blocks.
// Loads/stores stay lane-coalesced (v = t + 320*it), 10 f4/thread unrolled.
// Phase-B life/mask loads prefetched at entry to hide under phase A.
// ---------------------------------------------------------------------------
__global__ __launch_bounds__(320) void k_history(
    const float* __restrict__ hist_in, const float* __restrict__ mask,
    const float* __restrict__ life_in, const float* __restrict__ ws_means,
    const int* __restrict__ corr_idx, float* __restrict__ out) {
  __shared__ float sums[256];  // 1 KB

  const int t = threadIdx.x;
  const int pair0 = blockIdx.x * 256;
  const int i_row = pair0 >> 11;     // 256 | 2048 -> constant per block
  const int jbase = pair0 & 2047;

  int idx = corr_idx[0] % HIST;
  if (idx < 0) idx += HIST;

  // prefetch phase-B operands early (latency hides under phase A)
  const size_t pg = (size_t)pair0 + t;
  float lf = 0.f, mk = 0.f;
  if (t < 256) {
    lf = life_in[pg];
    mk = mask[pg];
    sums[t] = 0.f;
  }
  __syncthreads();

  const float mp_i = ws_means[i_row];
  const float* __restrict__ mpost = ws_means + PRE + jbase;
  const f32x4* __restrict__ hsrc4 =
      reinterpret_cast<const f32x4*>(hist_in + (size_t)pair0 * HIST);
  f32x4* __restrict__ hdst4 =
      reinterpret_cast<f32x4*>(out + OFF_HIST + (size_t)pair0 * HIST);

  // Phase A: 3200 f4 per block, 10 per thread, coalesced, fully unrolled
#pragma unroll
  for (int it = 0; it < 10; ++it) {
    const int v = t + it * 320;       // 0..3199 (local f4 index)
    const int f = v * 4;              // local float index 0..12796
    f32x4 x = hsrc4[v];
    const int p0 = f / 50;            // magic-mul, local pair 0..255
    const int h0 = f - p0 * 50;       // 0..49 (h0 <= 46 for last f4)
    float s_a = 0.f, s_b = 0.f;
#pragma unroll
    for (int e = 0; e < 4; ++e) {
      const bool hi = (h0 + e >= 50);
      const int h = hi ? (h0 + e - 50) : (h0 + e);
      const int p = hi ? (p0 + 1) : p0;
      float val = x[e];
      if (h == idx) { val = mp_i * mpost[p]; x[e] = val; }
      if (hi) s_b += val; else s_a += val;
    }
    atomicAdd(&sums[p0], s_a);
    if (h0 >= 47) atomicAdd(&sums[p0 + 1], s_b);  // f4 straddles pair boundary
    hdst4[v] = x;
  }
  __syncthreads();

  // Phase B: per-pair mean + lifetimes (threads 0..255), fully coalesced
  if (t < 256) {
    out[OFF_AVG + pg] = sums[t] * (1.0f / HIST);
    out[OFF_LIFE + pg] = lf + mk;
  }
}

// ---------------------------------------------------------------------------
extern "C" void kernel_launch(void* const* d_in, const int* in_sizes, int n_in,
                              void* d_out, int out_size, void* d_ws, size_t ws_size,
                              hipStream_t stream) {
  const float* pre   = (const float*)d_in[0];
  const float* post  = (const float*)d_in[1];
  // d_in[2] = current_time (unused: plasticity branch statically skipped)
  const float* W     = (const float*)d_in[3];
  const float* Mask  = (const float*)d_in[4];
  const float* preA  = (const float*)d_in[5];
  const float* postA = (const float*)d_in[6];
  const float* hist  = (const float*)d_in[7];
  const float* life  = (const float*)d_in[8];
  const int*   cidx  = (const int*)d_in[9];
  float* out = (float*)d_out;
  float* means = (float*)d_ws;  // 4096 floats scratch

  k_means<<<16, 256, 0, stream>>>(pre, post, preA, postA, out, means);
  k_matmul<<<512, 256, 0, stream>>>(pre, W, Mask, out);
  k_history<<<16384, 320, 0, stream>>>(hist, Mask, life, means, cidx, out);
}

// Round 8
// 1474.095 us; speedup vs baseline: 1.1886x; 1.0842x over previous
//
#include <hip/hip_runtime.h>

#define PRE   2048
#define POST  2048
#define BATCH 64
#define HIST  50

// output layout (floats), in reference return order
#define OFF_SYN      0           // [64][2048]
#define OFF_PRE_ACT  131072      // [2048]
#define OFF_POST_ACT 133120      // [2048]
#define OFF_HIST     135168      // [2048][2048][50]
#define OFF_LIFE     209850368   // [2048][2048]
#define OFF_AVG      214044672   // [2048][2048]

// workspace layout (floats)
#define WS_MEANS     0           // [4096] batch means
#define WS_PART      4096        // [32][131072] split-K partials (16.8 MB)
#define SYN_N        131072      // 64*2048

// native clang vector type
typedef float f32x4 __attribute__((ext_vector_type(4)));

// ---------------------------------------------------------------------------
// Kernel 1: batch means + EMA activity traces; also zero the synaptic_current
// region (needed only by the atomic fallback path, but harmless: 0.5 MB).
// grid 16 x 256
// ---------------------------------------------------------------------------
__global__ __launch_bounds__(256) void k_means(
    const float* __restrict__ pre, const float* __restrict__ post,
    const float* __restrict__ pre_act, const float* __restrict__ post_act,
    float* __restrict__ out, float* __restrict__ ws_means) {
  const int t = blockIdx.x * 256 + threadIdx.x;  // 0..4095

  f32x4* outz = reinterpret_cast<f32x4*>(out + OFF_SYN);
  const f32x4 z = {0.f, 0.f, 0.f, 0.f};
#pragma unroll
  for (int i = 0; i < 8; ++i) outz[t + i * 4096] = z;

  if (t < PRE) {
    float s = 0.f;
#pragma unroll 16
    for (int b = 0; b < BATCH; ++b) s += pre[b * PRE + t];
    const float m = s * (1.0f / BATCH);
    ws_means[t] = m;
    out[OFF_PRE_ACT + t] = 0.99f * pre_act[t] + 0.01f * m;
  } else {
    const int c = t - PRE;
    float s = 0.f;
#pragma unroll 16
    for (int b = 0; b < BATCH; ++b) s += post[b * POST + c];
    const float m = s * (1.0f / BATCH);
    ws_means[PRE + c] = m;
    out[OFF_POST_ACT + c] = 0.99f * post_act[c] + 0.01f * m;
  }
}

// ---------------------------------------------------------------------------
// Kernel 2a: split-K matmul writing PARTIALS to ws (no atomics).
// Grid 512 = 16 j-tiles(128) x 32 k-splits(64); 2 blocks/CU (32 KB LDS).
// Template flag selects atomic fallback (if ws too small).
// ---------------------------------------------------------------------------
template <bool USE_PART>
__global__ __launch_bounds__(256) void k_matmul(
    const float* __restrict__ pre, const float* __restrict__ W,
    const float* __restrict__ M, float* __restrict__ out,
    float* __restrict__ part) {
  __shared__ float ew[64 * 128];  // 32 KB

  const int jt = blockIdx.x & 15;  // 16 j-tiles of 128
  const int ks = blockIdx.x >> 4;  // 32 k-splits of 64
  const int j0 = jt * 128;
  const int k0 = ks * 64;
  const int t = threadIdx.x;

  // stage ew = W*M for [k0:k0+64][j0:j0+128]: 8192 floats = 2048 float4
#pragma unroll
  for (int it = 0; it < 8; ++it) {
    const int lin = (t + it * 256) * 4;  // 0..8188
    const int kk = lin >> 7;
    const int jj = lin & 127;
    const float4 w4 = *reinterpret_cast<const float4*>(&W[(k0 + kk) * POST + j0 + jj]);
    const float4 m4 = *reinterpret_cast<const float4*>(&M[(k0 + kk) * POST + j0 + jj]);
    float4 e;
    e.x = w4.x * m4.x; e.y = w4.y * m4.y; e.z = w4.z * m4.z; e.w = w4.w * m4.w;
    *reinterpret_cast<float4*>(&ew[kk * 128 + jj]) = e;
  }
  __syncthreads();

  const int tj = t & 15;   // 16 j-threads * 8 cols = 128
  const int tb = t >> 4;   // 16 b-groups * 4 rows = 64
  const int jb = tj * 8;
  const int bb0 = tb * 4;

  float acc[4][8];
#pragma unroll
  for (int r = 0; r < 4; ++r)
#pragma unroll
    for (int c = 0; c < 8; ++c) acc[r][c] = 0.f;

  const float4* ew4 = reinterpret_cast<const float4*>(ew);

#pragma unroll
  for (int kk4 = 0; kk4 < 16; ++kk4) {
    float4 pr[4];
#pragma unroll
    for (int r = 0; r < 4; ++r)
      pr[r] = *reinterpret_cast<const float4*>(&pre[(bb0 + r) * PRE + k0 + kk4 * 4]);
#pragma unroll
    for (int e = 0; e < 4; ++e) {
      const int kk = kk4 * 4 + e;
      const float4 e0 = ew4[kk * 32 + tj * 2];
      const float4 e1 = ew4[kk * 32 + tj * 2 + 1];
#pragma unroll
      for (int r = 0; r < 4; ++r) {
        const float pv = (e == 0) ? pr[r].x : (e == 1) ? pr[r].y : (e == 2) ? pr[r].z : pr[r].w;
        acc[r][0] += pv * e0.x; acc[r][1] += pv * e0.y;
        acc[r][2] += pv * e0.z; acc[r][3] += pv * e0.w;
        acc[r][4] += pv * e1.x; acc[r][5] += pv * e1.y;
        acc[r][6] += pv * e1.z; acc[r][7] += pv * e1.w;
      }
    }
  }

  if (USE_PART) {
    // plain coalesced stores of this split's partial tile
    float* dst = part + (size_t)ks * SYN_N;
#pragma unroll
    for (int r = 0; r < 4; ++r) {
      f32x4 lo = {acc[r][0], acc[r][1], acc[r][2], acc[r][3]};
      f32x4 hi = {acc[r][4], acc[r][5], acc[r][6], acc[r][7]};
      *reinterpret_cast<f32x4*>(&dst[(bb0 + r) * POST + j0 + jb])     = lo;
      *reinterpret_cast<f32x4*>(&dst[(bb0 + r) * POST + j0 + jb + 4]) = hi;
    }
  } else {
#pragma unroll
    for (int r = 0; r < 4; ++r)
#pragma unroll
      for (int c = 0; c < 8; ++c)
        unsafeAtomicAdd(&out[OFF_SYN + (bb0 + r) * POST + j0 + jb + c], acc[r][c]);
  }
}

// ---------------------------------------------------------------------------
// Kernel 2b: reduce 32 partials -> synaptic_current. 32768 f4 outputs.
// grid 32 x 256: thread handles 4 f4 (stride-256 within block's 1024-f4 span)
// ---------------------------------------------------------------------------
__global__ __launch_bounds__(256) void k_reduce(
    const float* __restrict__ part, float* __restrict__ out) {
  const f32x4* p4 = reinterpret_cast<const f32x4*>(part);
  f32x4* o4 = reinterpret_cast<f32x4*>(out + OFF_SYN);
#pragma unroll
  for (int i = 0; i < 4; ++i) {
    const int o = blockIdx.x * 1024 + i * 256 + threadIdx.x;  // 0..32767
    f32x4 s = {0.f, 0.f, 0.f, 0.f};
#pragma unroll
    for (int p = 0; p < 32; ++p) s += p4[(size_t)p * (SYN_N / 4) + o];
    o4[o] = s;
  }
}

// ---------------------------------------------------------------------------
// Kernel 3 (dominant): history copy + idx-slice replace + fused avg + life.
// Per-pair sums via ds_add_f32 into 1 KB sums[256]; occupancy thread-limited.
// Loads/stores lane-coalesced (v = t + 320*it), 10 f4/thread unrolled.
// ---------------------------------------------------------------------------
__global__ __launch_bounds__(320) void k_history(
    const float* __restrict__ hist_in, const float* __restrict__ mask,
    const float* __restrict__ life_in, const float* __restrict__ ws_means,
    const int* __restrict__ corr_idx, float* __restrict__ out) {
  __shared__ float sums[256];  // 1 KB

  const int t = threadIdx.x;
  const int pair0 = blockIdx.x * 256;
  const int i_row = pair0 >> 11;     // constant per block
  const int jbase = pair0 & 2047;

  int idx = corr_idx[0] % HIST;
  if (idx < 0) idx += HIST;

  // prefetch phase-B operands early (latency hides under phase A)
  const size_t pg = (size_t)pair0 + t;
  float lf = 0.f, mk = 0.f;
  if (t < 256) {
    lf = life_in[pg];
    mk = mask[pg];
    sums[t] = 0.f;
  }
  __syncthreads();

  const float mp_i = ws_means[i_row];
  const float* __restrict__ mpost = ws_means + PRE + jbase;
  const f32x4* __restrict__ hsrc4 =
      reinterpret_cast<const f32x4*>(hist_in + (size_t)pair0 * HIST);
  f32x4* __restrict__ hdst4 =
      reinterpret_cast<f32x4*>(out + OFF_HIST + (size_t)pair0 * HIST);

  // Phase A: 3200 f4 per block, 10 per thread, coalesced, fully unrolled
#pragma unroll
  for (int it = 0; it < 10; ++it) {
    const int v = t + it * 320;       // 0..3199 (local f4 index)
    const int f = v * 4;              // local float index
    f32x4 x = hsrc4[v];
    const int p0 = f / 50;            // magic-mul, local pair 0..255
    const int h0 = f - p0 * 50;       // 0..49
    float s_a = 0.f, s_b = 0.f;
#pragma unroll
    for (int e = 0; e < 4; ++e) {
      const bool hi = (h0 + e >= 50);
      const int h = hi ? (h0 + e - 50) : (h0 + e);
      const int p = hi ? (p0 + 1) : p0;
      float val = x[e];
      if (h == idx) { val = mp_i * mpost[p]; x[e] = val; }
      if (hi) s_b += val; else s_a += val;
    }
    atomicAdd(&sums[p0], s_a);
    if (h0 >= 47) atomicAdd(&sums[p0 + 1], s_b);  // f4 straddles pair boundary
    hdst4[v] = x;
  }
  __syncthreads();

  // Phase B: per-pair mean + lifetimes (threads 0..255), fully coalesced
  if (t < 256) {
    out[OFF_AVG + pg] = sums[t] * (1.0f / HIST);
    out[OFF_LIFE + pg] = lf + mk;
  }
}

// ---------------------------------------------------------------------------
extern "C" void kernel_launch(void* const* d_in, const int* in_sizes, int n_in,
                              void* d_out, int out_size, void* d_ws, size_t ws_size,
                              hipStream_t stream) {
  const float* pre   = (const float*)d_in[0];
  const float* post  = (const float*)d_in[1];
  // d_in[2] = current_time (unused: plasticity branch statically skipped)
  const float* W     = (const float*)d_in[3];
  const float* Mask  = (const float*)d_in[4];
  const float* preA  = (const float*)d_in[5];
  const float* postA = (const float*)d_in[6];
  const float* hist  = (const float*)d_in[7];
  const float* life  = (const float*)d_in[8];
  const int*   cidx  = (const int*)d_in[9];
  float* out = (float*)d_out;
  float* ws  = (float*)d_ws;
  float* means = ws + WS_MEANS;
  float* part  = ws + WS_PART;

  const bool use_part = ws_size >= (size_t)(WS_PART + 32 * SYN_N) * sizeof(float);

  k_means<<<16, 256, 0, stream>>>(pre, post, preA, postA, out, means);
  if (use_part) {
    k_matmul<true><<<512, 256, 0, stream>>>(pre, W, Mask, out, part);
    k_reduce<<<32, 256, 0, stream>>>(part, out);
  } else {
    k_matmul<false><<<512, 256, 0, stream>>>(pre, W, Mask, out, part);
  }
  k_history<<<16384, 320, 0, stream>>>(hist, Mask, life, means, cidx, out);
}

// Round 11
// 1452.046 us; speedup vs baseline: 1.2067x; 1.0152x over previous
//
#include <hip/hip_runtime.h>

#define PRE   2048
#define POST  2048
#define BATCH 64
#define HIST  50

// output layout (floats), in reference return order
#define OFF_SYN      0           // [64][2048]
#define OFF_PRE_ACT  131072      // [2048]
#define OFF_POST_ACT 133120      // [2048]
#define OFF_HIST     135168      // [2048][2048][50]
#define OFF_LIFE     209850368   // [2048][2048]
#define OFF_AVG      214044672   // [2048][2048]

// workspace layout (floats)
#define WS_MEANS     0           // [4096] batch means
#define WS_PART      4096        // [32][131072] split-K partials (16.8 MB)
#define SYN_N        131072      // 64*2048

// native clang vector type
typedef float f32x4 __attribute__((ext_vector_type(4)));

// ---------------------------------------------------------------------------
// Kernel 1: batch means + EMA activity traces; also zero the synaptic_current
// region (needed only by the atomic fallback path, but harmless: 0.5 MB).
// grid 16 x 256
// ---------------------------------------------------------------------------
__global__ __launch_bounds__(256) void k_means(
    const float* __restrict__ pre, const float* __restrict__ post,
    const float* __restrict__ pre_act, const float* __restrict__ post_act,
    float* __restrict__ out, float* __restrict__ ws_means) {
  const int t = blockIdx.x * 256 + threadIdx.x;  // 0..4095

  f32x4* outz = reinterpret_cast<f32x4*>(out + OFF_SYN);
  const f32x4 z = {0.f, 0.f, 0.f, 0.f};
#pragma unroll
  for (int i = 0; i < 8; ++i) outz[t + i * 4096] = z;

  if (t < PRE) {
    float s = 0.f;
#pragma unroll 16
    for (int b = 0; b < BATCH; ++b) s += pre[b * PRE + t];
    const float m = s * (1.0f / BATCH);
    ws_means[t] = m;
    out[OFF_PRE_ACT + t] = 0.99f * pre_act[t] + 0.01f * m;
  } else {
    const int c = t - PRE;
    float s = 0.f;
#pragma unroll 16
    for (int b = 0; b < BATCH; ++b) s += post[b * POST + c];
    const float m = s * (1.0f / BATCH);
    ws_means[PRE + c] = m;
    out[OFF_POST_ACT + c] = 0.99f * post_act[c] + 0.01f * m;
  }
}

// ---------------------------------------------------------------------------
// Kernel 2a: split-K matmul writing PARTIALS to ws (no atomics).
// Grid 512 = 16 j-tiles(128) x 32 k-splits(64); 2 blocks/CU (32 KB LDS).
// Template flag selects atomic fallback (if ws too small).
// ---------------------------------------------------------------------------
template <bool USE_PART>
__global__ __launch_bounds__(256) void k_matmul(
    const float* __restrict__ pre, const float* __restrict__ W,
    const float* __restrict__ M, float* __restrict__ out,
    float* __restrict__ part) {
  __shared__ float ew[64 * 128];  // 32 KB

  const int jt = blockIdx.x & 15;  // 16 j-tiles of 128
  const int ks = blockIdx.x >> 4;  // 32 k-splits of 64
  const int j0 = jt * 128;
  const int k0 = ks * 64;
  const int t = threadIdx.x;

  // stage ew = W*M for [k0:k0+64][j0:j0+128]: 8192 floats = 2048 float4
#pragma unroll
  for (int it = 0; it < 8; ++it) {
    const int lin = (t + it * 256) * 4;  // 0..8188
    const int kk = lin >> 7;
    const int jj = lin & 127;
    const float4 w4 = *reinterpret_cast<const float4*>(&W[(k0 + kk) * POST + j0 + jj]);
    const float4 m4 = *reinterpret_cast<const float4*>(&M[(k0 + kk) * POST + j0 + jj]);
    float4 e;
    e.x = w4.x * m4.x; e.y = w4.y * m4.y; e.z = w4.z * m4.z; e.w = w4.w * m4.w;
    *reinterpret_cast<float4*>(&ew[kk * 128 + jj]) = e;
  }
  __syncthreads();

  const int tj = t & 15;   // 16 j-threads * 8 cols = 128
  const int tb = t >> 4;   // 16 b-groups * 4 rows = 64
  const int jb = tj * 8;
  const int bb0 = tb * 4;

  float acc[4][8];
#pragma unroll
  for (int r = 0; r < 4; ++r)
#pragma unroll
    for (int c = 0; c < 8; ++c) acc[r][c] = 0.f;

  const float4* ew4 = reinterpret_cast<const float4*>(ew);

#pragma unroll
  for (int kk4 = 0; kk4 < 16; ++kk4) {
    float4 pr[4];
#pragma unroll
    for (int r = 0; r < 4; ++r)
      pr[r] = *reinterpret_cast<const float4*>(&pre[(bb0 + r) * PRE + k0 + kk4 * 4]);
#pragma unroll
    for (int e = 0; e < 4; ++e) {
      const int kk = kk4 * 4 + e;
      const float4 e0 = ew4[kk * 32 + tj * 2];
      const float4 e1 = ew4[kk * 32 + tj * 2 + 1];
#pragma unroll
      for (int r = 0; r < 4; ++r) {
        const float pv = (e == 0) ? pr[r].x : (e == 1) ? pr[r].y : (e == 2) ? pr[r].z : pr[r].w;
        acc[r][0] += pv * e0.x; acc[r][1] += pv * e0.y;
        acc[r][2] += pv * e0.z; acc[r][3] += pv * e0.w;
        acc[r][4] += pv * e1.x; acc[r][5] += pv * e1.y;
        acc[r][6] += pv * e1.z; acc[r][7] += pv * e1.w;
      }
    }
  }

  if (USE_PART) {
    // plain coalesced stores of this split's partial tile
    float* dst = part + (size_t)ks * SYN_N;
#pragma unroll
    for (int r = 0; r < 4; ++r) {
      f32x4 lo = {acc[r][0], acc[r][1], acc[r][2], acc[r][3]};
      f32x4 hi = {acc[r][4], acc[r][5], acc[r][6], acc[r][7]};
      *reinterpret_cast<f32x4*>(&dst[(bb0 + r) * POST + j0 + jb])     = lo;
      *reinterpret_cast<f32x4*>(&dst[(bb0 + r) * POST + j0 + jb + 4]) = hi;
    }
  } else {
#pragma unroll
    for (int r = 0; r < 4; ++r)
#pragma unroll
      for (int c = 0; c < 8; ++c)
        unsafeAtomicAdd(&out[OFF_SYN + (bb0 + r) * POST + j0 + jb + c], acc[r][c]);
  }
}

// ---------------------------------------------------------------------------
// Kernel 2b: reduce 32 partials -> synaptic_current. 32768 f4 outputs.
// grid 32 x 256: thread handles 4 f4 (stride-256 within block's 1024-f4 span)
// ---------------------------------------------------------------------------
__global__ __launch_bounds__(256) void k_reduce(
    const float* __restrict__ part, float* __restrict__ out) {
  const f32x4* p4 = reinterpret_cast<const f32x4*>(part);
  f32x4* o4 = reinterpret_cast<f32x4*>(out + OFF_SYN);
#pragma unroll
  for (int i = 0; i < 4; ++i) {
    const int o = blockIdx.x * 1024 + i * 256 + threadIdx.x;  // 0..32767
    f32x4 s = {0.f, 0.f, 0.f, 0.f};
#pragma unroll
    for (int p = 0; p < 32; ++p) s += p4[(size_t)p * (SYN_N / 4) + o];
    o4[o] = s;
  }
}

// ---------------------------------------------------------------------------
// Kernel 3 (dominant): history copy + idx-slice replace + fused avg + life.
// NO LDS atomics: phase A stores per-f4 partial pair {s_a (low pair), s_b
// (straddle into next pair)} via one conflict-free ds_write_b64 into
// sab[3200] (25.6 KB -> still 6 blocks/CU, thread-limited occupancy).
// Phase B: pair p gathers its 13 float2s starting at vlo = floor(12.5 p);
// term0 = .y for odd p (straddle from previous f4), else .x; terms 1..12 = .x.
// Loads/stores lane-coalesced (v = t + 320*it), 10 f4/thread unrolled.
// ---------------------------------------------------------------------------
__global__ __launch_bounds__(320) void k_history(
    const float* __restrict__ hist_in, const float* __restrict__ mask,
    const float* __restrict__ life_in, const float* __restrict__ ws_means,
    const int* __restrict__ corr_idx, float* __restrict__ out) {
  __shared__ float2 sab[3200];  // 25.6 KB

  const int t = threadIdx.x;
  const int pair0 = blockIdx.x * 256;
  const int i_row = pair0 >> 11;     // constant per block
  const int jbase = pair0 & 2047;

  int idx = corr_idx[0] % HIST;
  if (idx < 0) idx += HIST;

  // prefetch phase-B operands early (latency hides under phase A)
  const size_t pg = (size_t)pair0 + t;
  float lf = 0.f, mk = 0.f;
  if (t < 256) {
    lf = life_in[pg];
    mk = mask[pg];
  }

  const float mp_i = ws_means[i_row];
  const float* __restrict__ mpost = ws_means + PRE + jbase;
  const f32x4* __restrict__ hsrc4 =
      reinterpret_cast<const f32x4*>(hist_in + (size_t)pair0 * HIST);
  f32x4* __restrict__ hdst4 =
      reinterpret_cast<f32x4*>(out + OFF_HIST + (size_t)pair0 * HIST);

  // Phase A: 3200 f4 per block, 10 per thread, coalesced, fully unrolled
#pragma unroll
  for (int it = 0; it < 10; ++it) {
    const int v = t + it * 320;       // 0..3199 (local f4 index)
    const int f = v * 4;              // local float index
    f32x4 x = hsrc4[v];
    const int p0 = f / 50;            // magic-mul, local pair 0..255
    const int h0 = f - p0 * 50;       // 0..49
    float s_a = 0.f, s_b = 0.f;
#pragma unroll
    for (int e = 0; e < 4; ++e) {
      const bool hi = (h0 + e >= 50);
      const int h = hi ? (h0 + e - 50) : (h0 + e);
      const int p = hi ? (p0 + 1) : p0;
      float val = x[e];
      if (h == idx) { val = mp_i * mpost[p]; x[e] = val; }
      if (hi) s_b += val; else s_a += val;
    }
    sab[v] = make_float2(s_a, s_b);   // one ds_write_b64, conflict-free
    hdst4[v] = x;
  }
  __syncthreads();

  // Phase B: per-pair mean + lifetimes (threads 0..255), fully coalesced out
  if (t < 256) {
    const int vlo = (25 * t) >> 1;    // floor(12.5 * pair)
    const float2 first = sab[vlo];
    float s = (t & 1) ? first.y : first.x;
#pragma unroll
    for (int k = 1; k < 13; ++k) s += sab[vlo + k].x;
    out[OFF_AVG + pg] = s * (1.0f / HIST);
    out[OFF_LIFE + pg] = lf + mk;
  }
}

// ---------------------------------------------------------------------------
extern "C" void kernel_launch(void* const* d_in, const int* in_sizes, int n_in,
                              void* d_out, int out_size, void* d_ws, size_t ws_size,
                              hipStream_t stream) {
  const float* pre   = (const float*)d_in[0];
  const float* post  = (const float*)d_in[1];
  // d_in[2] = current_time (unused: plasticity branch statically skipped)
  const float* W     = (const float*)d_in[3];
  const float* Mask  = (const float*)d_in[4];
  const float* preA  = (const float*)d_in[5];
  const float* postA = (const float*)d_in[6];
  const float* hist  = (const float*)d_in[7];
  const float* life  = (const float*)d_in[8];
  const int*   cidx  = (const int*)d_in[9];
  float* out = (float*)d_out;
  float* ws  = (float*)d_ws;
  float* means = ws + WS_MEANS;
  float* part  = ws + WS_PART;

  const bool use_part = ws_size >= (size_t)(WS_PART + 32 * SYN_N) * sizeof(float);

  k_means<<<16, 256, 0, stream>>>(pre, post, preA, postA, out, means);
  if (use_part) {
    k_matmul<true><<<512, 256, 0, stream>>>(pre, W, Mask, out, part);
    k_reduce<<<32, 256, 0, stream>>>(part, out);
  } else {
    k_matmul<false><<<512, 256, 0, stream>>>(pre, W, Mask, out, part);
  }
  k_history<<<16384, 320, 0, stream>>>(hist, Mask, life, means, cidx, out);
}

// Round 16
// 1418.445 us; speedup vs baseline: 1.2353x; 1.0237x over previous
//
#include <hip/hip_runtime.h>

#define PRE   2048
#define POST  2048
#define BATCH 64
#define HIST  50

// output layout (floats), in reference return order
#define OFF_SYN      0           // [64][2048]
#define OFF_PRE_ACT  131072      // [2048]
#define OFF_POST_ACT 133120      // [2048]
#define OFF_HIST     135168      // [2048][2048][50]
#define OFF_LIFE     209850368   // [2048][2048]
#define OFF_AVG      214044672   // [2048][2048]

// workspace layout (floats)
#define WS_MEANS     0           // [4096] batch means
#define WS_PART      4096        // [32][131072] split-K partials (16.8 MB)
#define SYN_N        131072      // 64*2048

// native clang vector type (valid for __builtin_nontemporal_load/store)
typedef float f32x4 __attribute__((ext_vector_type(4)));

// ---------------------------------------------------------------------------
// Kernel 1: batch means + EMA activity traces; also zero the synaptic_current
// region (needed only by the atomic fallback path, but harmless: 0.5 MB).
// grid 16 x 256
// ---------------------------------------------------------------------------
__global__ __launch_bounds__(256) void k_means(
    const float* __restrict__ pre, const float* __restrict__ post,
    const float* __restrict__ pre_act, const float* __restrict__ post_act,
    float* __restrict__ out, float* __restrict__ ws_means) {
  const int t = blockIdx.x * 256 + threadIdx.x;  // 0..4095

  f32x4* outz = reinterpret_cast<f32x4*>(out + OFF_SYN);
  const f32x4 z = {0.f, 0.f, 0.f, 0.f};
#pragma unroll
  for (int i = 0; i < 8; ++i) outz[t + i * 4096] = z;

  if (t < PRE) {
    float s = 0.f;
#pragma unroll 16
    for (int b = 0; b < BATCH; ++b) s += pre[b * PRE + t];
    const float m = s * (1.0f / BATCH);
    ws_means[t] = m;
    out[OFF_PRE_ACT + t] = 0.99f * pre_act[t] + 0.01f * m;
  } else {
    const int c = t - PRE;
    float s = 0.f;
#pragma unroll 16
    for (int b = 0; b < BATCH; ++b) s += post[b * POST + c];
    const float m = s * (1.0f / BATCH);
    ws_means[PRE + c] = m;
    out[OFF_POST_ACT + c] = 0.99f * post_act[c] + 0.01f * m;
  }
}

// ---------------------------------------------------------------------------
// Kernel 2a: split-K matmul writing PARTIALS to ws (no atomics).
// Grid 512 = 16 j-tiles(128) x 32 k-splits(64); 2 blocks/CU (32 KB LDS).
// Template flag selects atomic fallback (if ws too small).
// ---------------------------------------------------------------------------
template <bool USE_PART>
__global__ __launch_bounds__(256) void k_matmul(
    const float* __restrict__ pre, const float* __restrict__ W,
    const float* __restrict__ M, float* __restrict__ out,
    float* __restrict__ part) {
  __shared__ float ew[64 * 128];  // 32 KB

  const int jt = blockIdx.x & 15;  // 16 j-tiles of 128
  const int ks = blockIdx.x >> 4;  // 32 k-splits of 64
  const int j0 = jt * 128;
  const int k0 = ks * 64;
  const int t = threadIdx.x;

  // stage ew = W*M for [k0:k0+64][j0:j0+128]: 8192 floats = 2048 float4
#pragma unroll
  for (int it = 0; it < 8; ++it) {
    const int lin = (t + it * 256) * 4;  // 0..8188
    const int kk = lin >> 7;
    const int jj = lin & 127;
    const float4 w4 = *reinterpret_cast<const float4*>(&W[(k0 + kk) * POST + j0 + jj]);
    const float4 m4 = *reinterpret_cast<const float4*>(&M[(k0 + kk) * POST + j0 + jj]);
    float4 e;
    e.x = w4.x * m4.x; e.y = w4.y * m4.y; e.z = w4.z * m4.z; e.w = w4.w * m4.w;
    *reinterpret_cast<float4*>(&ew[kk * 128 + jj]) = e;
  }
  __syncthreads();

  const int tj = t & 15;   // 16 j-threads * 8 cols = 128
  const int tb = t >> 4;   // 16 b-groups * 4 rows = 64
  const int jb = tj * 8;
  const int bb0 = tb * 4;

  float acc[4][8];
#pragma unroll
  for (int r = 0; r < 4; ++r)
#pragma unroll
    for (int c = 0; c < 8; ++c) acc[r][c] = 0.f;

  const float4* ew4 = reinterpret_cast<const float4*>(ew);

#pragma unroll
  for (int kk4 = 0; kk4 < 16; ++kk4) {
    float4 pr[4];
#pragma unroll
    for (int r = 0; r < 4; ++r)
      pr[r] = *reinterpret_cast<const float4*>(&pre[(bb0 + r) * PRE + k0 + kk4 * 4]);
#pragma unroll
    for (int e = 0; e < 4; ++e) {
      const int kk = kk4 * 4 + e;
      const float4 e0 = ew4[kk * 32 + tj * 2];
      const float4 e1 = ew4[kk * 32 + tj * 2 + 1];
#pragma unroll
      for (int r = 0; r < 4; ++r) {
        const float pv = (e == 0) ? pr[r].x : (e == 1) ? pr[r].y : (e == 2) ? pr[r].z : pr[r].w;
        acc[r][0] += pv * e0.x; acc[r][1] += pv * e0.y;
        acc[r][2] += pv * e0.z; acc[r][3] += pv * e0.w;
        acc[r][4] += pv * e1.x; acc[r][5] += pv * e1.y;
        acc[r][6] += pv * e1.z; acc[r][7] += pv * e1.w;
      }
    }
  }

  if (USE_PART) {
    // plain coalesced stores of this split's partial tile
    float* dst = part + (size_t)ks * SYN_N;
#pragma unroll
    for (int r = 0; r < 4; ++r) {
      f32x4 lo = {acc[r][0], acc[r][1], acc[r][2], acc[r][3]};
      f32x4 hi = {acc[r][4], acc[r][5], acc[r][6], acc[r][7]};
      *reinterpret_cast<f32x4*>(&dst[(bb0 + r) * POST + j0 + jb])     = lo;
      *reinterpret_cast<f32x4*>(&dst[(bb0 + r) * POST + j0 + jb + 4]) = hi;
    }
  } else {
#pragma unroll
    for (int r = 0; r < 4; ++r)
#pragma unroll
      for (int c = 0; c < 8; ++c)
        unsafeAtomicAdd(&out[OFF_SYN + (bb0 + r) * POST + j0 + jb + c], acc[r][c]);
  }
}

// ---------------------------------------------------------------------------
// Kernel 2b: reduce 32 partials -> synaptic_current. 32768 f4 outputs.
// grid 32 x 256: thread handles 4 f4 (stride-256 within block's 1024-f4 span)
// ---------------------------------------------------------------------------
__global__ __launch_bounds__(256) void k_reduce(
    const float* __restrict__ part, float* __restrict__ out) {
  const f32x4* p4 = reinterpret_cast<const f32x4*>(part);
  f32x4* o4 = reinterpret_cast<f32x4*>(out + OFF_SYN);
#pragma unroll
  for (int i = 0; i < 4; ++i) {
    const int o = blockIdx.x * 1024 + i * 256 + threadIdx.x;  // 0..32767
    f32x4 s = {0.f, 0.f, 0.f, 0.f};
#pragma unroll
    for (int p = 0; p < 32; ++p) s += p4[(size_t)p * (SYN_N / 4) + o];
    o4[o] = s;
  }
}

// ---------------------------------------------------------------------------
// Kernel 3 (dominant): history copy + idx-slice replace + fused avg + life.
// Single change vs measured R11: NONTEMPORAL load/store on the 1.68 GB
// history stream (zero reuse both directions) to bypass L2/L3 allocation.
// Phase A stores per-f4 partial pair {s_a, s_b} via conflict-free
// ds_write_b64 into sab[3200] (25.6 KB; occupancy thread-limited 6 blk/CU).
// Phase B: pair p gathers its 13 float2s from sab.
// ---------------------------------------------------------------------------
__global__ __launch_bounds__(320) void k_history(
    const float* __restrict__ hist_in, const float* __restrict__ mask,
    const float* __restrict__ life_in, const float* __restrict__ ws_means,
    const int* __restrict__ corr_idx, float* __restrict__ out) {
  __shared__ float2 sab[3200];  // 25.6 KB

  const int t = threadIdx.x;
  const int pair0 = blockIdx.x * 256;
  const int i_row = pair0 >> 11;     // constant per block
  const int jbase = pair0 & 2047;

  int idx = corr_idx[0] % HIST;
  if (idx < 0) idx += HIST;

  // prefetch phase-B operands early (latency hides under phase A)
  const size_t pg = (size_t)pair0 + t;
  float lf = 0.f, mk = 0.f;
  if (t < 256) {
    lf = life_in[pg];
    mk = mask[pg];
  }

  const float mp_i = ws_means[i_row];
  const float* __restrict__ mpost = ws_means + PRE + jbase;
  const f32x4* __restrict__ hsrc4 =
      reinterpret_cast<const f32x4*>(hist_in + (size_t)pair0 * HIST);
  f32x4* __restrict__ hdst4 =
      reinterpret_cast<f32x4*>(out + OFF_HIST + (size_t)pair0 * HIST);

  // Phase A: 3200 f4 per block, 10 per thread, coalesced, fully unrolled
#pragma unroll
  for (int it = 0; it < 10; ++it) {
    const int v = t + it * 320;       // 0..3199 (local f4 index)
    const int f = v * 4;              // local float index
    f32x4 x = __builtin_nontemporal_load(&hsrc4[v]);
    const int p0 = f / 50;            // magic-mul, local pair 0..255
    const int h0 = f - p0 * 50;       // 0..49
    float s_a = 0.f, s_b = 0.f;
#pragma unroll
    for (int e = 0; e < 4; ++e) {
      const bool hi = (h0 + e >= 50);
      const int h = hi ? (h0 + e - 50) : (h0 + e);
      const int p = hi ? (p0 + 1) : p0;
      float val = x[e];
      if (h == idx) { val = mp_i * mpost[p]; x[e] = val; }
      if (hi) s_b += val; else s_a += val;
    }
    sab[v] = make_float2(s_a, s_b);   // one ds_write_b64, conflict-free
    __builtin_nontemporal_store(x, &hdst4[v]);
  }
  __syncthreads();

  // Phase B: per-pair mean + lifetimes (threads 0..255), fully coalesced out
  if (t < 256) {
    const int vlo = (25 * t) >> 1;    // floor(12.5 * pair)
    const float2 first = sab[vlo];
    float s = (t & 1) ? first.y : first.x;
#pragma unroll
    for (int k = 1; k < 13; ++k) s += sab[vlo + k].x;
    out[OFF_AVG + pg] = s * (1.0f / HIST);
    out[OFF_LIFE + pg] = lf + mk;
  }
}

// ---------------------------------------------------------------------------
extern "C" void kernel_launch(void* const* d_in, const int* in_sizes, int n_in,
                              void* d_out, int out_size, void* d_ws, size_t ws_size,
                              hipStream_t stream) {
  const float* pre   = (const float*)d_in[0];
  const float* post  = (const float*)d_in[1];
  // d_in[2] = current_time (unused: plasticity branch statically skipped)
  const float* W     = (const float*)d_in[3];
  const float* Mask  = (const float*)d_in[4];
  const float* preA  = (const float*)d_in[5];
  const float* postA = (const float*)d_in[6];
  const float* hist  = (const float*)d_in[7];
  const float* life  = (const float*)d_in[8];
  const int*   cidx  = (const int*)d_in[9];
  float* out = (float*)d_out;
  float* ws  = (float*)d_ws;
  float* means = ws + WS_MEANS;
  float* part  = ws + WS_PART;

  const bool use_part = ws_size >= (size_t)(WS_PART + 32 * SYN_N) * sizeof(float);

  k_means<<<16, 256, 0, stream>>>(pre, post, preA, postA, out, means);
  if (use_part) {
    k_matmul<true><<<512, 256, 0, stream>>>(pre, W, Mask, out, part);
    k_reduce<<<32, 256, 0, stream>>>(part, out);
  } else {
    k_matmul<false><<<512, 256, 0, stream>>>(pre, W, Mask, out, part);
  }
  k_history<<<16384, 320, 0, stream>>>(hist, Mask, life, means, cidx, out);
}